// Round 6
// baseline (444.038 us; speedup 1.0000x reference)
//
#include <hip/hip_runtime.h>
#include <hip/hip_fp16.h>

#define BGR 32768
#define NNODE 19
#define NTOT (BGR*NNODE)       // 622592
#define EF 120
#define ES 60
#define NB 5
#define EPS 1e-5f

// ---- workspace layout (float offsets) ----
#define WS_U     0                          // NTOT*NB (band-major [b][node])
#define WS_PRE2  (WS_U + NTOT*NB)           // BGR*190 (node-major [g][(v*5+b)*2+kk])
#define WS_PRE3  (WS_PRE2 + BGR*190)        // BGR*128
#define WS_H2    (WS_PRE3 + BGR*128)        // NTOT*NB uints (half2, band-major)
#define WS_P3    (WS_H2 + NTOT*NB)          // 1024*256
#define WS_R3    (WS_P3 + 262144)           // 64*256
#define WS_P1    (WS_R3 + 16384)            // 8192*10
#define WS_P2    (WS_P1 + 81920)            // 8192*20
#define WS_WP    (WS_P2 + 163840)           // 192*128
#define WS_T1    (WS_WP + 24576)            // 165 float4
#define WS_A2    (WS_T1 + 660)
#define WS_D2    (WS_A2 + 16)
#define WS_A3    (WS_D2 + 16)
#define WS_D3    (WS_A3 + 128)

// ---------------- K1: dense-N GCN1 -> u (band-major) + block BN1 partials ----------------
__global__ __launch_bounds__(256) void k1_gcn1(
    const float* __restrict__ x, const float* __restrict__ ew,
    const int* __restrict__ srcf, const int* __restrict__ dstf,
    float* __restrict__ Ub, float* __restrict__ P1)
{
    __shared__ float xgb[4][100];      // band-major, pitch 20, col19 = pad(0); scaled by dinv[s]
    __shared__ float Nr[4][400];       // weighted adjacency [d][s], pitch 20, col19 = 0
    __shared__ float dinv[4][20];      // dinv[19] = 0
    __shared__ float ps[80];           // 8 copies x 10 stats
    int t = threadIdx.x, q = t >> 6, lane = t & 63;
    int g = blockIdx.x*4 + q;

    int s0, d0, s1 = 0, d1 = 0; float w0, w1 = 0.f;
    bool e1 = (lane < EF - 64);
    s0 = srcf[g*EF+lane] - g*NNODE; d0 = dstf[g*EF+lane] - g*NNODE; w0 = ew[g*EF+lane];
    if (e1) { s1 = srcf[g*EF+lane+64] - g*NNODE; d1 = dstf[g*EF+lane+64] - g*NNODE; w1 = ew[g*EF+lane+64]; }
    for (int j = lane; j < 100; j += 64) {
        int b = j/20, s = j - 20*b;
        xgb[q][j] = (s < 19) ? x[g*95 + s*5 + b] : 0.f;
    }
    for (int i = lane; i < 400; i += 64) Nr[q][i] = 0.f;
    if (t < 80) ps[t] = 0.f;
    __syncthreads();

    atomicAdd(&Nr[q][d0*20 + s0], w0);
    if (e1) atomicAdd(&Nr[q][d1*20 + s1], w1);
    __syncthreads();

    if (lane < 20) {
        float dv = 0.f;
        if (lane < 19) {
            float s = 0.f;
            #pragma unroll
            for (int k = 0; k < 19; k++) s += Nr[q][lane*20 + k];
            dv = rsqrtf(s + 1.f);
        }
        dinv[q][lane] = dv;
    }
    __syncthreads();
    for (int j = lane; j < 100; j += 64) xgb[q][j] *= dinv[q][j % 20];  // pad: 0*0 = 0
    __syncthreads();

    for (int i = lane; i < 95; i += 64) {
        int b = i/19, v = i - 19*b;
        float acc = xgb[q][b*20 + v];        // self: dinv[v]*x
        const float4* nrp = (const float4*)&Nr[q][v*20];
        const float4* xbp = (const float4*)&xgb[q][b*20];
        #pragma unroll
        for (int j = 0; j < 5; j++) {
            float4 n4 = nrp[j], x4 = xbp[j];
            acc += n4.x*x4.x + n4.y*x4.y + n4.z*x4.z + n4.w*x4.w;
        }
        float uv = dinv[q][v] * acc;
        Ub[(size_t)b*NTOT + g*19 + v] = uv;
        int c = lane & 7;
        atomicAdd(&ps[c*10 + b], uv);
        atomicAdd(&ps[c*10 + 5 + b], uv*uv);
    }
    __syncthreads();
    if (t < 10) {
        float s = 0.f;
        #pragma unroll
        for (int c = 0; c < 8; c++) s += ps[c*10 + t];
        P1[blockIdx.x*10 + t] = s;
    }
}

// ---------------- K2b: reduce P1[8192][10] -> BN1 stats -> T1 table ----------------
__global__ __launch_bounds__(1024) void k2b(const float* __restrict__ P1,
    const float* __restrict__ W1, const float* __restrict__ g1, const float* __restrict__ bt1,
    const float* __restrict__ W2, float4* __restrict__ T1)
{
    __shared__ float red[1000];
    __shared__ float tmp10[10], mean[5], varr[5];
    int t = threadIdx.x;
    if (t < 1000) {
        int col = t % 10, grp = t / 10;
        float acc = 0.f;
        for (int r = grp; r < 8192; r += 100) acc += P1[r*10 + col];
        red[t] = acc;
    }
    __syncthreads();
    if (t < 10) {
        float s = 0.f;
        for (int j = 0; j < 100; j++) s += red[j*10 + t];
        tmp10[t] = s;
    }
    __syncthreads();
    if (t < 5) {
        float m = tmp10[t] / (float)NTOT;
        mean[t] = m;
        varr[t] = tmp10[5+t] / (float)NTOT - m*m;
    }
    __syncthreads();
    if (t < 160) {
        int b = t >> 5;
        float w = W1[t];
        float c = w * rsqrtf(w*w*varr[b] + EPS) * g1[t];
        T1[b*33 + (t & 31)] = make_float4(c, bt1[t] - c*mean[b], W2[t*2], W2[t*2+1]);
    }
}

// ---------------- K3a: dense h2 map, band-uniform block, fully coalesced ----------------
__global__ __launch_bounds__(256) void k3a(
    const float* __restrict__ Ub, const float4* __restrict__ T1p,
    unsigned int* __restrict__ H2)
{
    int bb = blockIdx.x / (NTOT/256);
    int node = (blockIdx.x - bb*(NTOT/256))*256 + (int)threadIdx.x;
    float uv = Ub[(size_t)bb*NTOT + node];
    const float4* Tb = T1p + bb*33;
    float hx = 0.f, hy = 0.f;
    #pragma unroll
    for (int f = 0; f < 32; f++) {
        float4 c = Tb[f];
        float r = fmaxf(fmaf(c.x, uv, c.y), 0.f);
        hx = fmaf(r, c.z, hx);
        hy = fmaf(r, c.w, hy);
    }
    __half2 h = __floats2half2_rn(hx, hy);
    H2[(size_t)bb*NTOT + node] = *(unsigned int*)&h;
}

// ---------------- K3b: dense-M GCN2 aggregate + block BN2 partials ----------------
__global__ __launch_bounds__(256) void k3b(
    const unsigned int* __restrict__ H2, const int* __restrict__ srcs, const int* __restrict__ dsts,
    const float* __restrict__ b2, float2* __restrict__ pre2, float* __restrict__ P2)
{
    __shared__ float2 h2b[4][100];     // band-major pitch 20, scaled by dinv[s], col19 = 0
    __shared__ float  Mr[4][400];      // struct adjacency, pitch 20, col19 = 0
    __shared__ float  dinv[4][20];
    __shared__ float  b2l[12];
    __shared__ float  ps[160];         // 8 copies x 20
    int t = threadIdx.x, q = t >> 6, lane = t & 63;
    int g = blockIdx.x*4 + q;

    int b0 = lane/19, v0 = lane - 19*b0;
    unsigned int h0 = H2[(size_t)b0*NTOT + g*19 + v0];
    int b1 = (lane+64)/19, v1 = (lane+64) - 19*b1;
    unsigned int h1 = (lane < 31) ? H2[(size_t)b1*NTOT + g*19 + v1] : 0u;
    int ls = 0, ld = 0; bool ee = (lane < ES);
    if (ee) { ls = srcs[g*ES+lane] - g*NNODE; ld = dsts[g*ES+lane] - g*NNODE; }
    if (t < 10) b2l[t] = b2[t];
    if (t < 160) ps[t] = 0.f;
    for (int i = lane; i < 400; i += 64) Mr[q][i] = 0.f;
    __syncthreads();

    if (ee) atomicAdd(&Mr[q][ld*20 + ls], 1.f);
    __syncthreads();

    if (lane < 20) {
        float dv = 0.f;
        if (lane < 19) {
            float s = 0.f;
            #pragma unroll
            for (int k = 0; k < 19; k++) s += Mr[q][lane*20 + k];
            dv = rsqrtf(s + 1.f);
        }
        dinv[q][lane] = dv;
    }
    __syncthreads();

    {
        float2 f0 = __half22float2(*(__half2*)&h0);
        float sc = dinv[q][v0];
        h2b[q][b0*20 + v0] = make_float2(f0.x*sc, f0.y*sc);
        if (lane < 31) {
            float2 f1 = __half22float2(*(__half2*)&h1);
            float sc1 = dinv[q][v1];
            h2b[q][b1*20 + v1] = make_float2(f1.x*sc1, f1.y*sc1);
        }
        if (lane < 5) h2b[q][lane*20 + 19] = make_float2(0.f, 0.f);
    }
    __syncthreads();

    for (int i = lane; i < 95; i += 64) {
        int v = i/5, b = i - 5*v;
        float2 self = h2b[q][b*20 + v];
        float ax = self.x, ay = self.y;
        const float4* mp = (const float4*)&Mr[q][v*20];
        const float4* hp = (const float4*)&h2b[q][b*20];
        #pragma unroll
        for (int j = 0; j < 5; j++) {
            float4 m4 = mp[j];
            float4 hA = hp[2*j], hB = hp[2*j+1];
            ax += m4.x*hA.x + m4.y*hA.z + m4.z*hB.x + m4.w*hB.z;
            ay += m4.x*hA.y + m4.y*hA.w + m4.z*hB.y + m4.w*hB.w;
        }
        float dv = dinv[q][v];
        float ox = fmaf(dv, ax, b2l[2*b]);
        float oy = fmaf(dv, ay, b2l[2*b+1]);
        pre2[(size_t)g*95 + i] = make_float2(ox, oy);
        int c = lane & 7;
        atomicAdd(&ps[c*20 + 2*b],      ox);
        atomicAdd(&ps[c*20 + 2*b + 1],  oy);
        atomicAdd(&ps[c*20 + 10 + 2*b], ox*ox);
        atomicAdd(&ps[c*20 + 11 + 2*b], oy*oy);
    }
    __syncthreads();
    if (t < 20) {
        float s = 0.f;
        #pragma unroll
        for (int c = 0; c < 8; c++) s += ps[c*20 + t];
        P2[blockIdx.x*20 + t] = s;
    }
}

// ---------------- K4b: reduce P2[8192][20] -> A2,D2 ----------------
__global__ __launch_bounds__(1024) void k4b(const float* __restrict__ P2,
    const float* __restrict__ g2, const float* __restrict__ bt2,
    float* __restrict__ A2, float* __restrict__ D2)
{
    __shared__ float red[1000];
    __shared__ float tmp20[20];
    int t = threadIdx.x;
    if (t < 1000) {
        int col = t % 20, grp = t / 20;
        float acc = 0.f;
        for (int r = grp; r < 8192; r += 50) acc += P2[r*20 + col];
        red[t] = acc;
    }
    __syncthreads();
    if (t < 20) {
        float s = 0.f;
        for (int j = 0; j < 50; j++) s += red[j*20 + t];
        tmp20[t] = s;
    }
    __syncthreads();
    if (t < 10) {
        float m = tmp20[t] / (float)NTOT;
        float v = tmp20[10+t] / (float)NTOT - m*m;
        float a = g2[t] * rsqrtf(v + EPS);
        A2[t] = a;
        D2[t] = bt2[t] - a*m;
    }
}

// ---------------- KWP: permute lin1_W rows to xc k-order, pad to 192 rows ----------------
__global__ __launch_bounds__(256) void kwp(const float* __restrict__ W, float* __restrict__ Wp)
{
    int idx = blockIdx.x*256 + (int)threadIdx.x;   // 96 blocks -> 192*128
    int k = idx >> 7, f = idx & 127;
    float val = 0.f;
    if (k < 190) {
        int p = k >> 1, kk = k & 1;
        int v = p/5, b = p - 5*v;
        val = W[(b*38 + v*2 + kk)*128 + f];
    }
    Wp[idx] = val;
}

// ---------------- K5: pre3 = relu(BN2(pre2)) @ Wp + b. 32 graphs/block, 4 feats/lane ----------------
__global__ __launch_bounds__(256, 4) void k5_lin1(
    const float2* __restrict__ pre2, const float* __restrict__ A2, const float* __restrict__ D2,
    const float* __restrict__ Wp, const float* __restrict__ bias,
    float* __restrict__ pre3, float* __restrict__ p3)
{
    __shared__ float xg[32*192];       // 24.6 KB, k-padded to 192
    __shared__ float a2l[10], d2l[10];
    __shared__ float redS[8][128], redQ[8][128];
    int t = threadIdx.x, bid = blockIdx.x;
    if (t < 10) { a2l[t] = A2[t]; d2l[t] = D2[t]; }
    if (t < 64) xg[(t>>1)*192 + 190 + (t&1)] = 0.f;
    __syncthreads();

    const float2* src = pre2 + (size_t)bid*3040;
    for (int i = t; i < 3040; i += 256) {
        int gg = i / 95, p = i - gg*95;
        int b = p % 5;
        float2 v = src[i];
        xg[gg*192 + 2*p]     = fmaxf(fmaf(a2l[2*b],   v.x, d2l[2*b]),   0.f);
        xg[gg*192 + 2*p + 1] = fmaxf(fmaf(a2l[2*b+1], v.y, d2l[2*b+1]), 0.f);
    }
    __syncthreads();

    int lane = t & 63, h = t >> 6;
    int f32 = lane & 31, gh = lane >> 5;          // half-wave owns 4 graphs
    const float* xh = xg + (h*8 + gh*4)*192;
    float acc[4][4];                               // [graph r][feat group fg]
    #pragma unroll
    for (int r = 0; r < 4; r++)
        #pragma unroll
        for (int fg = 0; fg < 4; fg++) acc[r][fg] = 0.f;

    for (int kt = 0; kt < 24; kt++) {
        const float* wb = Wp + kt*8*128 + f32;
        float wv[4][8];
        #pragma unroll
        for (int fg = 0; fg < 4; fg++)
            #pragma unroll
            for (int j = 0; j < 8; j++) wv[fg][j] = wb[j*128 + 32*fg];
        #pragma unroll
        for (int r = 0; r < 4; r++) {
            float4 xa = *(const float4*)(xh + r*192 + kt*8);
            float4 xb = *(const float4*)(xh + r*192 + kt*8 + 4);
            #pragma unroll
            for (int fg = 0; fg < 4; fg++) {
                float a = acc[r][fg];
                a = fmaf(xa.x, wv[fg][0], a);
                a = fmaf(xa.y, wv[fg][1], a);
                a = fmaf(xa.z, wv[fg][2], a);
                a = fmaf(xa.w, wv[fg][3], a);
                a = fmaf(xb.x, wv[fg][4], a);
                a = fmaf(xb.y, wv[fg][5], a);
                a = fmaf(xb.z, wv[fg][6], a);
                a = fmaf(xb.w, wv[fg][7], a);
                acc[r][fg] = a;
            }
        }
    }

    int gbase = bid*32 + h*8 + gh*4;
    #pragma unroll
    for (int fg = 0; fg < 4; fg++) {
        int f = f32 + 32*fg;
        float bb = bias[f];
        float s = 0.f, qq = 0.f;
        #pragma unroll
        for (int r = 0; r < 4; r++) {
            float pv = acc[r][fg] + bb;
            pre3[(size_t)(gbase + r)*128 + f] = pv;
            s += pv; qq += pv*pv;
        }
        redS[h*2 + gh][f] = s;
        redQ[h*2 + gh][f] = qq;
    }
    __syncthreads();
    if (t < 128) {
        float s = 0.f;
        #pragma unroll
        for (int j = 0; j < 8; j++) s += redS[j][t];
        p3[bid*256 + t] = s;
    } else {
        int f = t - 128;
        float qq = 0.f;
        #pragma unroll
        for (int j = 0; j < 8; j++) qq += redQ[j][f];
        p3[bid*256 + 128 + f] = qq;
    }
}

// ---------------- K6a/K6b: BN3 stats reduction -> affine A3,D3 ----------------
__global__ __launch_bounds__(256) void k6a(const float* __restrict__ p3, float* __restrict__ r3)
{
    int j = blockIdx.x, f = threadIdx.x;
    float s = 0.f;
    for (int r = j*16; r < (j+1)*16; r++) s += p3[r*256 + f];
    r3[j*256 + f] = s;
}

__global__ __launch_bounds__(128) void k6b(const float* __restrict__ r3,
    const float* __restrict__ g3, const float* __restrict__ bt3,
    float* __restrict__ A3, float* __restrict__ D3)
{
    int f = threadIdx.x;
    float s = 0.f, q = 0.f;
    for (int j = 0; j < 64; j++) { s += r3[j*256 + f]; q += r3[j*256 + 128 + f]; }
    float m = s / (float)BGR;
    float v = q / (float)BGR - m*m;
    float a = g3[f] * rsqrtf(v + EPS);
    A3[f] = a;
    D3[f] = bt3[f] - a*m;
}

// ---------------- K7: head, thread per graph ----------------
__global__ __launch_bounds__(256) void k7_head(
    const float* __restrict__ pre3, const float* __restrict__ A3, const float* __restrict__ D3,
    const float* __restrict__ W2h, const float* __restrict__ b2h,
    const float* __restrict__ W3h, const float* __restrict__ b3h,
    float* __restrict__ out)
{
    int g = blockIdx.x*256 + threadIdx.x;
    float accj[32];
    #pragma unroll
    for (int j = 0; j < 32; j++) accj[j] = b2h[j];
    const float* p3 = pre3 + (size_t)g*128;
    #pragma unroll 2
    for (int f4 = 0; f4 < 128; f4 += 4) {
        float4 pv = *(const float4*)(p3 + f4);
        float y0 = fmaxf(fmaf(A3[f4+0], pv.x, D3[f4+0]), 0.f);
        float y1 = fmaxf(fmaf(A3[f4+1], pv.y, D3[f4+1]), 0.f);
        float y2 = fmaxf(fmaf(A3[f4+2], pv.z, D3[f4+2]), 0.f);
        float y3 = fmaxf(fmaf(A3[f4+3], pv.w, D3[f4+3]), 0.f);
        #pragma unroll
        for (int j = 0; j < 32; j++) {
            accj[j] = fmaf(y0, W2h[(f4+0)*32+j], accj[j]);
            accj[j] = fmaf(y1, W2h[(f4+1)*32+j], accj[j]);
            accj[j] = fmaf(y2, W2h[(f4+2)*32+j], accj[j]);
            accj[j] = fmaf(y3, W2h[(f4+3)*32+j], accj[j]);
        }
    }
    float o0 = b3h[0], o1 = b3h[1];
    #pragma unroll
    for (int j = 0; j < 32; j++) {
        float yj = fmaxf(accj[j], 0.f);
        o0 = fmaf(yj, W3h[j*2+0], o0);
        o1 = fmaf(yj, W3h[j*2+1], o1);
    }
    ((float2*)out)[g] = make_float2(o0, o1);
}

extern "C" void kernel_launch(void* const* d_in, const int* in_sizes, int n_in,
                              void* d_out, int out_size, void* d_ws, size_t ws_size,
                              hipStream_t stream)
{
    (void)in_sizes; (void)n_in; (void)out_size; (void)ws_size;
    const float* x    = (const float*)d_in[0];
    const float* ew   = (const float*)d_in[1];
    const int*   eif  = (const int*)d_in[2];
    const int*   eis  = (const int*)d_in[3];
    const float* W1   = (const float*)d_in[4];
    // d_in[5] = b1: cancels exactly inside BN1 (mean subtraction) — unused
    const float* g1   = (const float*)d_in[6];
    const float* bt1  = (const float*)d_in[7];
    const float* W2   = (const float*)d_in[8];
    const float* b2   = (const float*)d_in[9];
    const float* g2   = (const float*)d_in[10];
    const float* bt2  = (const float*)d_in[11];
    const float* l1W  = (const float*)d_in[12];
    const float* l1b  = (const float*)d_in[13];
    const float* g3   = (const float*)d_in[14];
    const float* bt3  = (const float*)d_in[15];
    const float* l2W  = (const float*)d_in[16];
    const float* l2b  = (const float*)d_in[17];
    const float* l3W  = (const float*)d_in[18];
    const float* l3b  = (const float*)d_in[19];
    float* out = (float*)d_out;
    float* ws  = (float*)d_ws;

    const int* srcf = eif;  const int* dstf = eif + BGR*EF;
    const int* srcs = eis;  const int* dsts = eis + BGR*ES;

    float* U    = ws + WS_U;
    float* PRE2 = ws + WS_PRE2;
    float* PRE3 = ws + WS_PRE3;
    unsigned int* H2 = (unsigned int*)(ws + WS_H2);
    float* P3   = ws + WS_P3;
    float* R3   = ws + WS_R3;
    float* P1   = ws + WS_P1;
    float* P2   = ws + WS_P2;
    float* WP   = ws + WS_WP;
    float4* T1  = (float4*)(ws + WS_T1);
    float* A2   = ws + WS_A2;
    float* D2   = ws + WS_D2;
    float* A3   = ws + WS_A3;
    float* D3   = ws + WS_D3;

    kwp<<<96, 256, 0, stream>>>(l1W, WP);
    k1_gcn1<<<BGR/4, 256, 0, stream>>>(x, ew, srcf, dstf, U, P1);
    k2b<<<1, 1024, 0, stream>>>(P1, W1, g1, bt1, W2, T1);
    k3a<<<(NTOT/256)*5, 256, 0, stream>>>(U, T1, H2);
    k3b<<<BGR/4, 256, 0, stream>>>(H2, srcs, dsts, b2, (float2*)PRE2, P2);
    k4b<<<1, 1024, 0, stream>>>(P2, g2, bt2, A2, D2);
    k5_lin1<<<1024, 256, 0, stream>>>((const float2*)PRE2, A2, D2, WP, l1b, PRE3, P3);
    k6a<<<64, 256, 0, stream>>>(P3, R3);
    k6b<<<1, 128, 0, stream>>>(R3, g3, bt3, A3, D3);
    k7_head<<<BGR/256, 256, 0, stream>>>(PRE3, A3, D3, l2W, l2b, l3W, l3b, out);
}

// Round 7
// 375.968 us; speedup vs baseline: 1.1811x; 1.1811x over previous
//
#include <hip/hip_runtime.h>

#define BGR 32768
#define NNODE 19
#define NTOT (BGR*NNODE)       // 622592
#define EF 120
#define ES 60
#define NB 5
#define EPS 1e-5f

// ---- workspace layout (float offsets) ----
#define WS_U     0                          // NTOT*NB (node-major [g][v*5+b])
#define WS_PRE2  (WS_U + NTOT*NB)           // BGR*190 (node-major [g][(v*5+b)*2+kk])
#define WS_PRE3  (WS_PRE2 + BGR*190)        // BGR*128
#define WS_P3    (WS_PRE3 + BGR*128)        // 1024*256
#define WS_R3    (WS_P3 + 262144)           // 64*256
#define WS_P1    (WS_R3 + 16384)            // 160*10
#define WS_R2    (WS_P1 + 1600)             // 320*20
#define WS_WP    (WS_R2 + 6400)             // 128*192
#define WS_T1    (WS_WP + 24576)            // 165 float4 = 660
#define WS_TB    (WS_T1 + 660)              // 165 (+3 pad)
#define WS_TSEG  (WS_TB + 168)              // 165 float4 = 660
#define WS_A2    (WS_TSEG + 660)
#define WS_D2    (WS_A2 + 16)
#define WS_A3    (WS_D2 + 16)
#define WS_D3    (WS_A3 + 128)

// ---------------- K1: dense-N GCN1 -> u (node-major). wave/graph, 4 graphs/block ----------------
// Nr pitch 21 (odd): banks 21*v mod 32 distinct for v=0..18 -> conflict-free row reads.
__global__ __launch_bounds__(256) void k1_gcn1(
    const float* __restrict__ x, const float* __restrict__ ew,
    const int* __restrict__ srcf, const int* __restrict__ dstf,
    float* __restrict__ U)
{
    __shared__ float xg[4][96];        // node-major [s*5+b], scaled by dinv[s] in place
    __shared__ float Nr[4][400];       // weighted adjacency [d][s], pitch 21
    __shared__ float dinv[4][20];
    int t = threadIdx.x, q = t >> 6, lane = t & 63;
    int g = blockIdx.x*4 + q;

    int s0, d0, s1 = 0, d1 = 0; float w0, w1 = 0.f;
    bool e1 = (lane < EF - 64);
    s0 = srcf[g*EF+lane] - g*NNODE; d0 = dstf[g*EF+lane] - g*NNODE; w0 = ew[g*EF+lane];
    if (e1) { s1 = srcf[g*EF+lane+64] - g*NNODE; d1 = dstf[g*EF+lane+64] - g*NNODE; w1 = ew[g*EF+lane+64]; }
    for (int i = lane; i < 95; i += 64) xg[q][i] = x[g*95 + i];
    for (int i = lane; i < 400; i += 64) Nr[q][i] = 0.f;
    __syncthreads();

    atomicAdd(&Nr[q][d0*21 + s0], w0);
    if (e1) atomicAdd(&Nr[q][d1*21 + s1], w1);
    __syncthreads();

    if (lane < NNODE) {
        float s = 0.f;
        #pragma unroll
        for (int k = 0; k < 19; k++) s += Nr[q][lane*21 + k];
        dinv[q][lane] = rsqrtf(s + 1.f);
    }
    __syncthreads();
    for (int i = lane; i < 95; i += 64) xg[q][i] *= dinv[q][i/5];   // xg := dinv[s]*x[s][b]
    __syncthreads();

    for (int i = lane; i < 95; i += 64) {
        int v = i/5, b = i - 5*v;
        float acc = xg[q][i];                // self: dinv[v]*(dinv[v]*x)
        #pragma unroll
        for (int s = 0; s < 19; s++) acc += Nr[q][v*21 + s] * xg[q][s*5 + b];
        U[(size_t)g*95 + i] = dinv[q][v] * acc;
    }
}

// ---------------- KR1: per-band sum & sumsq over node-major U, coalesced ----------------
__global__ __launch_bounds__(256) void kr1(const float* __restrict__ U, float* __restrict__ P1)
{
    int t = threadIdx.x;
    const int CH = NTOT*NB/160;        // 19456
    size_t base = (size_t)blockIdx.x * CH;
    float s[5], qq[5];
    #pragma unroll
    for (int b = 0; b < 5; b++) { s[b] = 0.f; qq[b] = 0.f; }
    int m = (int)((base + t) % 5);
    for (int n = 0; n < CH/256; n++) {               // 76 iters
        float v = U[base + n*256 + t];
        #pragma unroll
        for (int b = 0; b < 5; b++) {
            bool hit = (m == b);
            s[b]  += hit ? v   : 0.f;
            qq[b] += hit ? v*v : 0.f;
        }
        m++; if (m == 5) m = 0;                       // +256 ≡ +1 mod 5
    }
    __shared__ float red[256][10];
    #pragma unroll
    for (int b = 0; b < 5; b++) { red[t][b] = s[b]; red[t][5+b] = qq[b]; }
    __syncthreads();
    for (int off = 128; off > 0; off >>= 1) {
        if (t < off) {
            #pragma unroll
            for (int k = 0; k < 10; k++) red[t][k] += red[t+off][k];
        }
        __syncthreads();
    }
    if (t < 10) P1[blockIdx.x*10 + t] = red[0][t];
}

// ---------------- K2b: reduce P1[160][10] -> BN1 stats -> T1 table ----------------
__global__ __launch_bounds__(256) void k2b(const float* __restrict__ P1,
    const float* __restrict__ W1, const float* __restrict__ g1, const float* __restrict__ bt1,
    const float* __restrict__ W2, float4* __restrict__ T1)
{
    __shared__ float red[16][10];
    __shared__ float mean[5], varr[5];
    int t = threadIdx.x;
    if (t < 160) {
        int col = t % 10, grp = t / 10;
        float acc = 0.f;
        for (int j = 0; j < 10; j++) acc += P1[(grp*10 + j)*10 + col];
        red[grp][col] = acc;
    }
    __syncthreads();
    if (t < 10) {
        float ss = 0.f;
        #pragma unroll
        for (int j = 0; j < 16; j++) ss += red[j][t];
        red[0][t] = ss;
    }
    __syncthreads();
    if (t < 5) {
        float m = red[0][t] / (float)NTOT;
        mean[t] = m;
        varr[t] = red[0][5+t] / (float)NTOT - m*m;
    }
    __syncthreads();
    if (t < 160) {
        int b = t >> 5;
        float w = W1[t];
        float c = w * rsqrtf(w*w*varr[b] + EPS) * g1[t];
        T1[b*33 + (t & 31)] = make_float4(c, bt1[t] - c*mean[b], W2[t*2], W2[t*2+1]);
    }
}

// ---------------- KPWL: build piecewise-linear table of h2(u) per band ----------------
// h2x(u) = sum_f wx_f * relu(a_f*u + d_f) is PWL with 32 breakpoints t_f = -d_f/a_f.
// Output: TB[b*33 + r] sorted breakpoints (r<32) + FLT_MAX sentinel at r=32;
//         TSEG[b*33 + j] = (Sx,Cx,Sy,Cy) of segment j (j=0..32): h = S*u + C.
__global__ __launch_bounds__(256) void kpwl(const float4* __restrict__ T1,
    float* __restrict__ TB, float4* __restrict__ TSEG)
{
    __shared__ float  traw[5][32];
    __shared__ float4 dlt[5][32];
    __shared__ float  acc0[5][4];
    int t = threadIdx.x;
    if (t < 20) ((float*)acc0)[t] = 0.f;
    __syncthreads();

    int b = 0, f = 0; float a = 0.f, d = 0.f, wx = 0.f, wy = 0.f, tf = 0.f; bool dg = true;
    if (t < 160) {
        b = t >> 5; f = t & 31;
        float4 c4 = T1[b*33 + f];
        a = c4.x; d = c4.y; wx = c4.z; wy = c4.w;
        dg = (fabsf(a) < 1e-30f);
        tf = dg ? 3.0e38f : (-d/a);
        traw[b][f] = tf;
        if (dg) {
            float rd = fmaxf(d, 0.f);
            atomicAdd(&acc0[b][1], wx*rd);
            atomicAdd(&acc0[b][3], wy*rd);
        } else if (a < 0.f) {
            atomicAdd(&acc0[b][0], wx*a);
            atomicAdd(&acc0[b][1], wx*d);
            atomicAdd(&acc0[b][2], wy*a);
            atomicAdd(&acc0[b][3], wy*d);
        }
    }
    __syncthreads();
    if (t < 160) {
        int r = 0;
        #pragma unroll
        for (int ff = 0; ff < 32; ff++) {
            float o = traw[b][ff];
            r += (o < tf || (o == tf && ff < f)) ? 1 : 0;
        }
        TB[b*33 + r] = tf;
        float4 dl = make_float4(0.f, 0.f, 0.f, 0.f);
        if (!dg) {
            float sgn = (a > 0.f) ? 1.f : -1.f;
            dl = make_float4(sgn*wx*a, sgn*wx*d, sgn*wy*a, sgn*wy*d);
        }
        dlt[b][r] = dl;
    }
    if (t < 5) TB[t*33 + 32] = 3.0e38f;
    __syncthreads();
    if (t < 5) {
        float sx = acc0[t][0], cx = acc0[t][1], sy = acc0[t][2], cy = acc0[t][3];
        TSEG[t*33 + 0] = make_float4(sx, cx, sy, cy);
        for (int r = 0; r < 32; r++) {
            float4 dl = dlt[t][r];
            sx += dl.x; cx += dl.y; sy += dl.z; cy += dl.w;
            TSEG[t*33 + r + 1] = make_float4(sx, cx, sy, cy);
        }
    }
}

// ---------------- K3b: fused PWL-h2 + dense-M GCN2. wave/graph, 4 graphs/block ----------------
__global__ __launch_bounds__(256) void k3b(
    const float* __restrict__ U, const int* __restrict__ srcs, const int* __restrict__ dsts,
    const float* __restrict__ TBg, const float4* __restrict__ TSEGg,
    const float* __restrict__ b2, float2* __restrict__ pre2)
{
    __shared__ float  tt[168];         // sorted breakpoints + sentinel, [b*33+r]
    __shared__ float4 tseg[165];       // segment (Sx,Cx,Sy,Cy)
    __shared__ float2 h2l[4][96];      // node-major [s*5+b], scaled by dinv[s]
    __shared__ float  Mr[4][400];      // struct adjacency [d][s], pitch 21
    __shared__ float  dinv[4][20];
    __shared__ float  b2l[12];
    int t = threadIdx.x, q = t >> 6, lane = t & 63;
    int g = blockIdx.x*4 + q;

    if (t < 165) { tt[t] = TBg[t]; tseg[t] = TSEGg[t]; }
    float u0 = U[(size_t)g*95 + lane];
    float u1 = (lane < 31) ? U[(size_t)g*95 + lane + 64] : 0.f;
    int ls = 0, ld = 0; bool ee = (lane < ES);
    if (ee) { ls = srcs[g*ES+lane] - g*NNODE; ld = dsts[g*ES+lane] - g*NNODE; }
    if (t < 10) b2l[t] = b2[t];
    for (int i = lane; i < 400; i += 64) Mr[q][i] = 0.f;
    __syncthreads();

    if (ee) atomicAdd(&Mr[q][ld*21 + ls], 1.f);
    __syncthreads();

    if (lane < NNODE) {
        float s = 0.f;
        #pragma unroll
        for (int k = 0; k < 19; k++) s += Mr[q][lane*21 + k];
        dinv[q][lane] = rsqrtf(s + 1.f);
    }
    __syncthreads();

    // PWL evaluate h2 for this lane's 1-2 nodes, scale by dinv[s], store
    {
        int v0 = lane/5, b0 = lane - 5*v0;
        int j = 0;
        #pragma unroll
        for (int st = 32; st > 0; st >>= 1) {
            int nx = j + st;
            if (nx <= 32 && u0 >= tt[b0*33 + nx - 1]) j = nx;
        }
        float4 sc = tseg[b0*33 + j];
        float dv = dinv[q][v0];
        h2l[q][lane] = make_float2(dv*fmaf(sc.x, u0, sc.y), dv*fmaf(sc.z, u0, sc.w));
        if (lane < 31) {
            int i1 = lane + 64, v1 = i1/5, b1 = i1 - 5*v1;
            int j1 = 0;
            #pragma unroll
            for (int st = 32; st > 0; st >>= 1) {
                int nx = j1 + st;
                if (nx <= 32 && u1 >= tt[b1*33 + nx - 1]) j1 = nx;
            }
            float4 sc1 = tseg[b1*33 + j1];
            float dv1 = dinv[q][v1];
            h2l[q][i1] = make_float2(dv1*fmaf(sc1.x, u1, sc1.y), dv1*fmaf(sc1.z, u1, sc1.w));
        }
    }
    __syncthreads();

    for (int i = lane; i < 95; i += 64) {
        int v = i/5, b = i - 5*v;
        float2 self = h2l[q][i];
        float ax = self.x, ay = self.y;
        #pragma unroll
        for (int s = 0; s < 19; s++) {
            float m = Mr[q][v*21 + s];
            float2 hh = h2l[q][s*5 + b];
            ax = fmaf(m, hh.x, ax);
            ay = fmaf(m, hh.y, ay);
        }
        float dv = dinv[q][v];
        pre2[(size_t)g*95 + i] = make_float2(fmaf(dv, ax, b2l[2*b]),
                                             fmaf(dv, ay, b2l[2*b+1]));
    }
}

// ---------------- KR2: per-(b,k) sum & sumsq over PRE2, coalesced, 320 blocks ----------------
__global__ __launch_bounds__(256) void kr2(const float2* __restrict__ pre2, float* __restrict__ r2)
{
    int t = threadIdx.x;
    size_t base = (size_t)blockIdx.x * 9728;          // 320*9728 = BGR*95
    float sx[5], sy[5], qx[5], qy[5];
    #pragma unroll
    for (int b = 0; b < 5; b++) { sx[b]=0.f; sy[b]=0.f; qx[b]=0.f; qy[b]=0.f; }
    for (int n = 0; n < 38; n++) {
        size_t i = base + n*256 + t;
        float2 v = pre2[i];
        int p = (int)(i % 95);
        int b = p % 5;
        #pragma unroll
        for (int bb = 0; bb < 5; bb++) {
            bool m = (b == bb);
            sx[bb] += m ? v.x : 0.f;     sy[bb] += m ? v.y : 0.f;
            qx[bb] += m ? v.x*v.x : 0.f; qy[bb] += m ? v.y*v.y : 0.f;
        }
    }
    __shared__ float red[256][20];
    #pragma unroll
    for (int b = 0; b < 5; b++) {
        red[t][2*b] = sx[b];      red[t][2*b+1] = sy[b];
        red[t][10+2*b] = qx[b];   red[t][11+2*b] = qy[b];
    }
    __syncthreads();
    for (int off = 128; off > 0; off >>= 1) {
        if (t < off) {
            #pragma unroll
            for (int k = 0; k < 20; k++) red[t][k] += red[t+off][k];
        }
        __syncthreads();
    }
    if (t < 20) r2[blockIdx.x*20 + t] = red[0][t];
}

// ---------------- K4b: finalize BN2 stats -> A2,D2 (320 partials) ----------------
__global__ __launch_bounds__(320) void k4b(const float* __restrict__ r2,
    const float* __restrict__ g2, const float* __restrict__ bt2,
    float* __restrict__ A2, float* __restrict__ D2)
{
    __shared__ float part[16][20];
    int t = threadIdx.x;
    int col = t % 20, grp = t / 20;
    float s = 0.f;
    for (int j = 0; j < 20; j++) s += r2[(grp*20 + j)*20 + col];
    part[grp][col] = s;
    __syncthreads();
    if (t < 20) {
        float ss = 0.f;
        #pragma unroll
        for (int j = 0; j < 16; j++) ss += part[j][t];
        part[0][t] = ss;
    }
    __syncthreads();
    if (t < 10) {
        float m = part[0][t] / (float)NTOT;
        float v = part[0][10+t] / (float)NTOT - m*m;
        float a = g2[t] * rsqrtf(v + EPS);
        A2[t] = a;
        D2[t] = bt2[t] - a*m;
    }
}

// ---------------- KWP: permute+transpose lin1_W -> Wp[128][192] (k in xc order, padded) ----------------
__global__ __launch_bounds__(256) void kwp(const float* __restrict__ W, float* __restrict__ Wp)
{
    int idx = blockIdx.x*256 + (int)threadIdx.x;   // 96 blocks -> 128*192
    int f = idx / 192, k = idx - 192*f;
    float val = 0.f;
    if (k < 190) {
        int p = k >> 1, kk = k & 1;
        int v = p/5, b = p - 5*v;
        val = W[(b*38 + v*2 + kk)*128 + f];
    }
    Wp[idx] = val;
}

// ---------------- K5: pre3 = relu(BN2(pre2)) @ Wp^T + b. 32 graphs/block, 4 feats/lane ----------------
__global__ __launch_bounds__(256, 4) void k5_lin1(
    const float2* __restrict__ pre2, const float* __restrict__ A2, const float* __restrict__ D2,
    const float* __restrict__ Wp, const float* __restrict__ bias,
    float* __restrict__ pre3, float* __restrict__ p3)
{
    __shared__ float xg[32*192];       // 24.6 KB, k-padded to 192
    __shared__ float a2l[10], d2l[10];
    __shared__ float redS[8][128], redQ[8][128];
    int t = threadIdx.x, bid = blockIdx.x;
    if (t < 10) { a2l[t] = A2[t]; d2l[t] = D2[t]; }
    if (t < 64) xg[(t>>1)*192 + 190 + (t&1)] = 0.f;
    __syncthreads();

    const float2* src = pre2 + (size_t)bid*3040;
    for (int i = t; i < 3040; i += 256) {
        int gg = i / 95, p = i - gg*95;
        int b = p % 5;
        float2 v = src[i];
        xg[gg*192 + 2*p]     = fmaxf(fmaf(a2l[2*b],   v.x, d2l[2*b]),   0.f);
        xg[gg*192 + 2*p + 1] = fmaxf(fmaf(a2l[2*b+1], v.y, d2l[2*b+1]), 0.f);
    }
    __syncthreads();

    int lane = t & 63, h = t >> 6;
    int f32 = lane & 31, gh = lane >> 5;          // half-wave owns 4 graphs
    const float* xh = xg + (h*8 + gh*4)*192;
    float acc[4][4];
    #pragma unroll
    for (int r = 0; r < 4; r++)
        #pragma unroll
        for (int fg = 0; fg < 4; fg++) acc[r][fg] = 0.f;

    for (int kt = 0; kt < 24; kt++) {
        float4 w0[4], w1[4];
        #pragma unroll
        for (int fg = 0; fg < 4; fg++) {
            const float4* wp = (const float4*)(Wp + (f32 + 32*fg)*192 + kt*8);
            w0[fg] = wp[0]; w1[fg] = wp[1];
        }
        #pragma unroll
        for (int r = 0; r < 4; r++) {
            float4 xa = *(const float4*)(xh + r*192 + kt*8);
            float4 xb = *(const float4*)(xh + r*192 + kt*8 + 4);
            #pragma unroll
            for (int fg = 0; fg < 4; fg++) {
                float a = acc[r][fg];
                a = fmaf(xa.x, w0[fg].x, a);
                a = fmaf(xa.y, w0[fg].y, a);
                a = fmaf(xa.z, w0[fg].z, a);
                a = fmaf(xa.w, w0[fg].w, a);
                a = fmaf(xb.x, w1[fg].x, a);
                a = fmaf(xb.y, w1[fg].y, a);
                a = fmaf(xb.z, w1[fg].z, a);
                a = fmaf(xb.w, w1[fg].w, a);
                acc[r][fg] = a;
            }
        }
    }

    int gbase = bid*32 + h*8 + gh*4;
    #pragma unroll
    for (int fg = 0; fg < 4; fg++) {
        int f = f32 + 32*fg;
        float bb = bias[f];
        float s = 0.f, qq = 0.f;
        #pragma unroll
        for (int r = 0; r < 4; r++) {
            float pv = acc[r][fg] + bb;
            pre3[(size_t)(gbase + r)*128 + f] = pv;
            s += pv; qq += pv*pv;
        }
        redS[h*2 + gh][f] = s;
        redQ[h*2 + gh][f] = qq;
    }
    __syncthreads();
    if (t < 128) {
        float s = 0.f;
        #pragma unroll
        for (int j = 0; j < 8; j++) s += redS[j][t];
        p3[bid*256 + t] = s;
    } else {
        int f = t - 128;
        float qq = 0.f;
        #pragma unroll
        for (int j = 0; j < 8; j++) qq += redQ[j][f];
        p3[bid*256 + 128 + f] = qq;
    }
}

// ---------------- K6a/K6b: BN3 stats reduction -> affine A3,D3 ----------------
__global__ __launch_bounds__(256) void k6a(const float* __restrict__ p3, float* __restrict__ r3)
{
    int j = blockIdx.x, f = threadIdx.x;
    float s = 0.f;
    for (int r = j*16; r < (j+1)*16; r++) s += p3[r*256 + f];
    r3[j*256 + f] = s;
}

__global__ __launch_bounds__(128) void k6b(const float* __restrict__ r3,
    const float* __restrict__ g3, const float* __restrict__ bt3,
    float* __restrict__ A3, float* __restrict__ D3)
{
    int f = threadIdx.x;
    float s = 0.f, q = 0.f;
    for (int j = 0; j < 64; j++) { s += r3[j*256 + f]; q += r3[j*256 + 128 + f]; }
    float m = s / (float)BGR;
    float v = q / (float)BGR - m*m;
    float a = g3[f] * rsqrtf(v + EPS);
    A3[f] = a;
    D3[f] = bt3[f] - a*m;
}

// ---------------- K7: head, thread per graph ----------------
__global__ __launch_bounds__(256) void k7_head(
    const float* __restrict__ pre3, const float* __restrict__ A3, const float* __restrict__ D3,
    const float* __restrict__ W2h, const float* __restrict__ b2h,
    const float* __restrict__ W3h, const float* __restrict__ b3h,
    float* __restrict__ out)
{
    int g = blockIdx.x*256 + threadIdx.x;
    float accj[32];
    #pragma unroll
    for (int j = 0; j < 32; j++) accj[j] = b2h[j];
    const float* p3 = pre3 + (size_t)g*128;
    #pragma unroll 2
    for (int f4 = 0; f4 < 128; f4 += 4) {
        float4 pv = *(const float4*)(p3 + f4);
        float y0 = fmaxf(fmaf(A3[f4+0], pv.x, D3[f4+0]), 0.f);
        float y1 = fmaxf(fmaf(A3[f4+1], pv.y, D3[f4+1]), 0.f);
        float y2 = fmaxf(fmaf(A3[f4+2], pv.z, D3[f4+2]), 0.f);
        float y3 = fmaxf(fmaf(A3[f4+3], pv.w, D3[f4+3]), 0.f);
        #pragma unroll
        for (int j = 0; j < 32; j++) {
            accj[j] = fmaf(y0, W2h[(f4+0)*32+j], accj[j]);
            accj[j] = fmaf(y1, W2h[(f4+1)*32+j], accj[j]);
            accj[j] = fmaf(y2, W2h[(f4+2)*32+j], accj[j]);
            accj[j] = fmaf(y3, W2h[(f4+3)*32+j], accj[j]);
        }
    }
    float o0 = b3h[0], o1 = b3h[1];
    #pragma unroll
    for (int j = 0; j < 32; j++) {
        float yj = fmaxf(accj[j], 0.f);
        o0 = fmaf(yj, W3h[j*2+0], o0);
        o1 = fmaf(yj, W3h[j*2+1], o1);
    }
    ((float2*)out)[g] = make_float2(o0, o1);
}

extern "C" void kernel_launch(void* const* d_in, const int* in_sizes, int n_in,
                              void* d_out, int out_size, void* d_ws, size_t ws_size,
                              hipStream_t stream)
{
    (void)in_sizes; (void)n_in; (void)out_size; (void)ws_size;
    const float* x    = (const float*)d_in[0];
    const float* ew   = (const float*)d_in[1];
    const int*   eif  = (const int*)d_in[2];
    const int*   eis  = (const int*)d_in[3];
    const float* W1   = (const float*)d_in[4];
    // d_in[5] = b1: cancels exactly inside BN1 (mean subtraction) — unused
    const float* g1   = (const float*)d_in[6];
    const float* bt1  = (const float*)d_in[7];
    const float* W2   = (const float*)d_in[8];
    const float* b2   = (const float*)d_in[9];
    const float* g2   = (const float*)d_in[10];
    const float* bt2  = (const float*)d_in[11];
    const float* l1W  = (const float*)d_in[12];
    const float* l1b  = (const float*)d_in[13];
    const float* g3   = (const float*)d_in[14];
    const float* bt3  = (const float*)d_in[15];
    const float* l2W  = (const float*)d_in[16];
    const float* l2b  = (const float*)d_in[17];
    const float* l3W  = (const float*)d_in[18];
    const float* l3b  = (const float*)d_in[19];
    float* out = (float*)d_out;
    float* ws  = (float*)d_ws;

    const int* srcf = eif;  const int* dstf = eif + BGR*EF;
    const int* srcs = eis;  const int* dsts = eis + BGR*ES;

    float* U    = ws + WS_U;
    float* PRE2 = ws + WS_PRE2;
    float* PRE3 = ws + WS_PRE3;
    float* P3   = ws + WS_P3;
    float* R3   = ws + WS_R3;
    float* P1   = ws + WS_P1;
    float* R2   = ws + WS_R2;
    float* WP   = ws + WS_WP;
    float4* T1  = (float4*)(ws + WS_T1);
    float* TB   = ws + WS_TB;
    float4* TSEG= (float4*)(ws + WS_TSEG);
    float* A2   = ws + WS_A2;
    float* D2   = ws + WS_D2;
    float* A3   = ws + WS_A3;
    float* D3   = ws + WS_D3;

    kwp<<<96, 256, 0, stream>>>(l1W, WP);
    k1_gcn1<<<BGR/4, 256, 0, stream>>>(x, ew, srcf, dstf, U);
    kr1<<<160, 256, 0, stream>>>(U, P1);
    k2b<<<1, 256, 0, stream>>>(P1, W1, g1, bt1, W2, T1);
    kpwl<<<1, 256, 0, stream>>>(T1, TB, TSEG);
    k3b<<<BGR/4, 256, 0, stream>>>(U, srcs, dsts, TB, TSEG, b2, (float2*)PRE2);
    kr2<<<320, 256, 0, stream>>>((const float2*)PRE2, R2);
    k4b<<<1, 320, 0, stream>>>(R2, g2, bt2, A2, D2);
    k5_lin1<<<1024, 256, 0, stream>>>((const float2*)PRE2, A2, D2, WP, l1b, PRE3, P3);
    k6a<<<64, 256, 0, stream>>>(P3, R3);
    k6b<<<1, 128, 0, stream>>>(R3, g3, bt3, A3, D3);
    k7_head<<<BGR/256, 256, 0, stream>>>(PRE3, A3, D3, l2W, l2b, l3W, l3b, out);
}

// Round 8
// 307.782 us; speedup vs baseline: 1.4427x; 1.2215x over previous
//
#include <hip/hip_runtime.h>

#define BGR 32768
#define NNODE 19
#define NTOT (BGR*NNODE)       // 622592
#define EF 120
#define ES 60
#define NB 5
#define EPS 1e-5f

// ---- workspace layout (float offsets) ----
#define WS_U     0                          // NTOT*NB (node-major [g][v*5+b])
#define WS_PRE2  (WS_U + NTOT*NB)           // BGR*190 (node-major [g][(v*5+b)*2+kk])
#define WS_PRE3  (WS_PRE2 + BGR*190)        // BGR*128
#define WS_P3    (WS_PRE3 + BGR*128)        // 1024*256
#define WS_R3    (WS_P3 + 262144)           // 64*256
#define WS_P1    (WS_R3 + 16384)            // 160*10
#define WS_R2    (WS_P1 + 1600)             // 320*20
#define WS_WP    (WS_R2 + 6400)             // 192*128 (k-major)
#define WS_TB    (WS_WP + 24576)            // 168
#define WS_TSEG  (WS_TB + 168)              // 165 float4 = 660
#define WS_END   (WS_TSEG + 660)

// ---------------- K1: dense-N GCN1 -> u (node-major). wave/graph, 4 graphs/block ----------------
// Nr pitch 21 (odd): banks 21*v mod 32 distinct for v=0..18 -> conflict-free row reads.
__global__ __launch_bounds__(256) void k1_gcn1(
    const float* __restrict__ x, const float* __restrict__ ew,
    const int* __restrict__ srcf, const int* __restrict__ dstf,
    float* __restrict__ U)
{
    __shared__ float xg[4][96];        // node-major [s*5+b], scaled by dinv[s] in place
    __shared__ float Nr[4][400];       // weighted adjacency [d][s], pitch 21
    __shared__ float dinv[4][20];
    int t = threadIdx.x, q = t >> 6, lane = t & 63;
    int g = blockIdx.x*4 + q;

    int s0, d0, s1 = 0, d1 = 0; float w0, w1 = 0.f;
    bool e1 = (lane < EF - 64);
    s0 = srcf[g*EF+lane] - g*NNODE; d0 = dstf[g*EF+lane] - g*NNODE; w0 = ew[g*EF+lane];
    if (e1) { s1 = srcf[g*EF+lane+64] - g*NNODE; d1 = dstf[g*EF+lane+64] - g*NNODE; w1 = ew[g*EF+lane+64]; }
    for (int i = lane; i < 95; i += 64) xg[q][i] = x[g*95 + i];
    for (int i = lane; i < 400; i += 64) Nr[q][i] = 0.f;
    __syncthreads();

    atomicAdd(&Nr[q][d0*21 + s0], w0);
    if (e1) atomicAdd(&Nr[q][d1*21 + s1], w1);
    __syncthreads();

    if (lane < NNODE) {
        float s = 0.f;
        #pragma unroll
        for (int k = 0; k < 19; k++) s += Nr[q][lane*21 + k];
        dinv[q][lane] = rsqrtf(s + 1.f);
    }
    __syncthreads();
    for (int i = lane; i < 95; i += 64) xg[q][i] *= dinv[q][i/5];   // xg := dinv[s]*x[s][b]
    __syncthreads();

    for (int i = lane; i < 95; i += 64) {
        int v = i/5, b = i - 5*v;
        float acc = xg[q][i];                // self: dinv[v]*(dinv[v]*x)
        #pragma unroll
        for (int s = 0; s < 19; s++) acc += Nr[q][v*21 + s] * xg[q][s*5 + b];
        U[(size_t)g*95 + i] = dinv[q][v] * acc;
    }
}

// ---------------- KR1: U stats -> P1; blocks 0..95 also build Wp[192][128] ----------------
__global__ __launch_bounds__(256) void kr1(const float* __restrict__ U, float* __restrict__ P1,
    const float* __restrict__ W, float* __restrict__ Wp)
{
    int t = threadIdx.x;
    if (blockIdx.x < 96) {                  // fold of old kwp: permute lin1_W rows to xc k-order
        int idx = blockIdx.x*256 + t;       // 96*256 = 192*128
        int k = idx >> 7, f = idx & 127;
        float val = 0.f;
        if (k < 190) {
            int p = k >> 1, kk = k & 1;
            int v = p/5, b = p - 5*v;
            val = W[(b*38 + v*2 + kk)*128 + f];
        }
        Wp[idx] = val;
    }
    const int CH = NTOT*NB/160;             // 19456
    size_t base = (size_t)blockIdx.x * CH;
    float s[5], qq[5];
    #pragma unroll
    for (int b = 0; b < 5; b++) { s[b] = 0.f; qq[b] = 0.f; }
    int m = (int)((base + t) % 5);
    for (int n = 0; n < CH/256; n++) {      // 76 iters
        float v = U[base + n*256 + t];
        #pragma unroll
        for (int b = 0; b < 5; b++) {
            bool hit = (m == b);
            s[b]  += hit ? v   : 0.f;
            qq[b] += hit ? v*v : 0.f;
        }
        m++; if (m == 5) m = 0;
    }
    __shared__ float red[256][10];
    #pragma unroll
    for (int b = 0; b < 5; b++) { red[t][b] = s[b]; red[t][5+b] = qq[b]; }
    __syncthreads();
    for (int off = 128; off > 0; off >>= 1) {
        if (t < off) {
            #pragma unroll
            for (int k = 0; k < 10; k++) red[t][k] += red[t+off][k];
        }
        __syncthreads();
    }
    if (t < 10) P1[blockIdx.x*10 + t] = red[0][t];
}

// ---------------- K2C: P1 -> BN1 stats -> T1 (LDS) -> PWL tables TB/TSEG ----------------
__global__ __launch_bounds__(256) void k2c(const float* __restrict__ P1,
    const float* __restrict__ W1, const float* __restrict__ g1, const float* __restrict__ bt1,
    const float* __restrict__ W2, float* __restrict__ TB, float4* __restrict__ TSEG)
{
    __shared__ float red[16][10];
    __shared__ float mean[5], varr[5];
    __shared__ float4 T1s[160];        // [b*32+f]
    __shared__ float  traw[5][32];
    __shared__ float4 dlt[5][32];
    __shared__ float  acc0[5][4];
    int t = threadIdx.x;

    if (t < 160) {
        int col = t % 10, grp = t / 10;
        float acc = 0.f;
        for (int j = 0; j < 10; j++) acc += P1[(grp*10 + j)*10 + col];
        red[grp][col] = acc;
    }
    if (t < 20) ((float*)acc0)[t] = 0.f;
    __syncthreads();
    if (t < 10) {
        float ss = 0.f;
        #pragma unroll
        for (int j = 0; j < 16; j++) ss += red[j][t];
        red[0][t] = ss;
    }
    __syncthreads();
    if (t < 5) {
        float m = red[0][t] / (float)NTOT;
        mean[t] = m;
        varr[t] = red[0][5+t] / (float)NTOT - m*m;
    }
    __syncthreads();

    int b = 0, f = 0; float a = 0.f, d = 0.f, wx = 0.f, wy = 0.f, tf = 0.f; bool dg = true;
    if (t < 160) {
        b = t >> 5; f = t & 31;
        float w = W1[t];
        a = w * rsqrtf(w*w*varr[b] + EPS) * g1[t];
        d = bt1[t] - a*mean[b];
        wx = W2[t*2]; wy = W2[t*2+1];
        dg = (fabsf(a) < 1e-30f);
        tf = dg ? 3.0e38f : (-d/a);
        traw[b][f] = tf;
        if (dg) {
            float rd = fmaxf(d, 0.f);
            atomicAdd(&acc0[b][1], wx*rd);
            atomicAdd(&acc0[b][3], wy*rd);
        } else if (a < 0.f) {
            atomicAdd(&acc0[b][0], wx*a);
            atomicAdd(&acc0[b][1], wx*d);
            atomicAdd(&acc0[b][2], wy*a);
            atomicAdd(&acc0[b][3], wy*d);
        }
    }
    __syncthreads();
    if (t < 160) {
        int r = 0;
        #pragma unroll
        for (int ff = 0; ff < 32; ff++) {
            float o = traw[b][ff];
            r += (o < tf || (o == tf && ff < f)) ? 1 : 0;
        }
        TB[b*33 + r] = tf;
        float4 dl = make_float4(0.f, 0.f, 0.f, 0.f);
        if (!dg) {
            float sgn = (a > 0.f) ? 1.f : -1.f;
            dl = make_float4(sgn*wx*a, sgn*wx*d, sgn*wy*a, sgn*wy*d);
        }
        dlt[b][r] = dl;
    }
    if (t < 5) TB[t*33 + 32] = 3.0e38f;
    __syncthreads();
    if (t < 5) {
        float sx = acc0[t][0], cx = acc0[t][1], sy = acc0[t][2], cy = acc0[t][3];
        TSEG[t*33 + 0] = make_float4(sx, cx, sy, cy);
        for (int r = 0; r < 32; r++) {
            float4 dl = dlt[t][r];
            sx += dl.x; cx += dl.y; sy += dl.z; cy += dl.w;
            TSEG[t*33 + r + 1] = make_float4(sx, cx, sy, cy);
        }
    }
    (void)T1s;
}

// ---------------- K3b: fused PWL-h2 + dense-M GCN2. wave/graph, 4 graphs/block ----------------
__global__ __launch_bounds__(256) void k3b(
    const float* __restrict__ U, const int* __restrict__ srcs, const int* __restrict__ dsts,
    const float* __restrict__ TBg, const float4* __restrict__ TSEGg,
    const float* __restrict__ b2, float2* __restrict__ pre2)
{
    __shared__ float  tt[168];
    __shared__ float4 tseg[165];
    __shared__ float2 h2l[4][96];
    __shared__ float  Mr[4][400];      // pitch 21
    __shared__ float  dinv[4][20];
    __shared__ float  b2l[12];
    int t = threadIdx.x, q = t >> 6, lane = t & 63;
    int g = blockIdx.x*4 + q;

    if (t < 165) { tt[t] = TBg[t]; tseg[t] = TSEGg[t]; }
    float u0 = U[(size_t)g*95 + lane];
    float u1 = (lane < 31) ? U[(size_t)g*95 + lane + 64] : 0.f;
    int ls = 0, ld = 0; bool ee = (lane < ES);
    if (ee) { ls = srcs[g*ES+lane] - g*NNODE; ld = dsts[g*ES+lane] - g*NNODE; }
    if (t < 10) b2l[t] = b2[t];
    for (int i = lane; i < 400; i += 64) Mr[q][i] = 0.f;
    __syncthreads();

    if (ee) atomicAdd(&Mr[q][ld*21 + ls], 1.f);
    __syncthreads();

    if (lane < NNODE) {
        float s = 0.f;
        #pragma unroll
        for (int k = 0; k < 19; k++) s += Mr[q][lane*21 + k];
        dinv[q][lane] = rsqrtf(s + 1.f);
    }
    __syncthreads();

    {
        int v0 = lane/5, b0 = lane - 5*v0;
        int j = 0;
        #pragma unroll
        for (int st = 32; st > 0; st >>= 1) {
            int nx = j + st;
            if (nx <= 32 && u0 >= tt[b0*33 + nx - 1]) j = nx;
        }
        float4 sc = tseg[b0*33 + j];
        float dv = dinv[q][v0];
        h2l[q][lane] = make_float2(dv*fmaf(sc.x, u0, sc.y), dv*fmaf(sc.z, u0, sc.w));
        if (lane < 31) {
            int i1 = lane + 64, v1 = i1/5, b1 = i1 - 5*v1;
            int j1 = 0;
            #pragma unroll
            for (int st = 32; st > 0; st >>= 1) {
                int nx = j1 + st;
                if (nx <= 32 && u1 >= tt[b1*33 + nx - 1]) j1 = nx;
            }
            float4 sc1 = tseg[b1*33 + j1];
            float dv1 = dinv[q][v1];
            h2l[q][i1] = make_float2(dv1*fmaf(sc1.x, u1, sc1.y), dv1*fmaf(sc1.z, u1, sc1.w));
        }
    }
    __syncthreads();

    for (int i = lane; i < 95; i += 64) {
        int v = i/5, b = i - 5*v;
        float2 self = h2l[q][i];
        float ax = self.x, ay = self.y;
        #pragma unroll
        for (int s = 0; s < 19; s++) {
            float m = Mr[q][v*21 + s];
            float2 hh = h2l[q][s*5 + b];
            ax = fmaf(m, hh.x, ax);
            ay = fmaf(m, hh.y, ay);
        }
        float dv = dinv[q][v];
        pre2[(size_t)g*95 + i] = make_float2(fmaf(dv, ax, b2l[2*b]),
                                             fmaf(dv, ay, b2l[2*b+1]));
    }
}

// ---------------- KR2: per-(b,k) sum & sumsq over PRE2, coalesced, 320 blocks ----------------
__global__ __launch_bounds__(256) void kr2(const float2* __restrict__ pre2, float* __restrict__ r2)
{
    int t = threadIdx.x;
    size_t base = (size_t)blockIdx.x * 9728;
    float sx[5], sy[5], qx[5], qy[5];
    #pragma unroll
    for (int b = 0; b < 5; b++) { sx[b]=0.f; sy[b]=0.f; qx[b]=0.f; qy[b]=0.f; }
    for (int n = 0; n < 38; n++) {
        size_t i = base + n*256 + t;
        float2 v = pre2[i];
        int p = (int)(i % 95);
        int b = p % 5;
        #pragma unroll
        for (int bb = 0; bb < 5; bb++) {
            bool m = (b == bb);
            sx[bb] += m ? v.x : 0.f;     sy[bb] += m ? v.y : 0.f;
            qx[bb] += m ? v.x*v.x : 0.f; qy[bb] += m ? v.y*v.y : 0.f;
        }
    }
    __shared__ float red[256][20];
    #pragma unroll
    for (int b = 0; b < 5; b++) {
        red[t][2*b] = sx[b];      red[t][2*b+1] = sy[b];
        red[t][10+2*b] = qx[b];   red[t][11+2*b] = qy[b];
    }
    __syncthreads();
    for (int off = 128; off > 0; off >>= 1) {
        if (t < off) {
            #pragma unroll
            for (int k = 0; k < 20; k++) red[t][k] += red[t+off][k];
        }
        __syncthreads();
    }
    if (t < 20) r2[blockIdx.x*20 + t] = red[0][t];
}

// ---------------- K5: folds BN2-finalize + relu(BN2(pre2)) @ Wp + b. 32 graphs/block ----------------
// lane owns feats 4*f32..4*f32+3 -> W loads are coalesced float4 at Wp[k*128+4*f32].
__global__ __launch_bounds__(256, 4) void k5_lin1(
    const float2* __restrict__ pre2, const float* __restrict__ R2,
    const float* __restrict__ g2, const float* __restrict__ bt2,
    const float* __restrict__ Wp, const float* __restrict__ bias,
    float* __restrict__ pre3, float* __restrict__ p3)
{
    __shared__ float xg[32*192];       // 24.6 KB, k-padded to 192
    __shared__ float a2l[10], d2l[10];
    __shared__ float r20[12][20];
    __shared__ float redS[8][128], redQ[8][128];
    int t = threadIdx.x, bid = blockIdx.x;

    if (t < 240) {                      // fold of old k4b: A2/D2 from R2[320][20]
        int col = t % 20, grp = t / 20;
        float s = 0.f;
        for (int j = grp; j < 320; j += 12) s += R2[j*20 + col];
        r20[grp][col] = s;
    }
    if (t >= 240 && t < 240+16) {
        int i = t - 240;                // zero k-pad cols 190,191 for 8 rows each... covered below
    }
    __syncthreads();
    if (t < 20) {
        float s = 0.f;
        #pragma unroll
        for (int j = 0; j < 12; j++) s += r20[j][t];
        r20[0][t] = s;
    }
    if (t < 64) xg[(t>>1)*192 + 190 + (t&1)] = 0.f;
    __syncthreads();
    if (t < 10) {
        float m = r20[0][t] / (float)NTOT;
        float v = r20[0][10+t] / (float)NTOT - m*m;
        float a = g2[t] * rsqrtf(v + EPS);
        a2l[t] = a;
        d2l[t] = bt2[t] - a*m;
    }
    __syncthreads();

    const float2* src = pre2 + (size_t)bid*3040;
    for (int i = t; i < 3040; i += 256) {
        int gg = i / 95, p = i - gg*95;
        int b = p % 5;
        float2 v = src[i];
        xg[gg*192 + 2*p]     = fmaxf(fmaf(a2l[2*b],   v.x, d2l[2*b]),   0.f);
        xg[gg*192 + 2*p + 1] = fmaxf(fmaf(a2l[2*b+1], v.y, d2l[2*b+1]), 0.f);
    }
    __syncthreads();

    int lane = t & 63, h = t >> 6;
    int f32 = lane & 31, gh = lane >> 5;          // half-wave owns 4 graphs; lane: feats 4f32..+3
    const float* xh = xg + (h*8 + gh*4)*192;
    float acc[4][4];                               // [graph r][feat c]
    #pragma unroll
    for (int r = 0; r < 4; r++)
        #pragma unroll
        for (int c = 0; c < 4; c++) acc[r][c] = 0.f;

    for (int kt = 0; kt < 24; kt++) {
        float4 w[8];
        #pragma unroll
        for (int j = 0; j < 8; j++)
            w[j] = *(const float4*)(Wp + (kt*8 + j)*128 + 4*f32);   // coalesced 512B/quarter-wave
        #pragma unroll
        for (int r = 0; r < 4; r++) {
            float4 xa = *(const float4*)(xh + r*192 + kt*8);
            float4 xb = *(const float4*)(xh + r*192 + kt*8 + 4);
            #pragma unroll
            for (int c = 0; c < 4; c++) {
                float a = acc[r][c];
                a = fmaf(xa.x, ((const float*)&w[0])[c], a);
                a = fmaf(xa.y, ((const float*)&w[1])[c], a);
                a = fmaf(xa.z, ((const float*)&w[2])[c], a);
                a = fmaf(xa.w, ((const float*)&w[3])[c], a);
                a = fmaf(xb.x, ((const float*)&w[4])[c], a);
                a = fmaf(xb.y, ((const float*)&w[5])[c], a);
                a = fmaf(xb.z, ((const float*)&w[6])[c], a);
                a = fmaf(xb.w, ((const float*)&w[7])[c], a);
                acc[r][c] = a;
            }
        }
    }

    int gbase = bid*32 + h*8 + gh*4;
    float4 b4 = *(const float4*)(bias + 4*f32);
    float s4[4] = {0.f,0.f,0.f,0.f}, q4[4] = {0.f,0.f,0.f,0.f};
    #pragma unroll
    for (int r = 0; r < 4; r++) {
        float4 pv;
        pv.x = acc[r][0] + b4.x;
        pv.y = acc[r][1] + b4.y;
        pv.z = acc[r][2] + b4.z;
        pv.w = acc[r][3] + b4.w;
        *(float4*)(pre3 + (size_t)(gbase + r)*128 + 4*f32) = pv;    // coalesced
        s4[0]+=pv.x; s4[1]+=pv.y; s4[2]+=pv.z; s4[3]+=pv.w;
        q4[0]+=pv.x*pv.x; q4[1]+=pv.y*pv.y; q4[2]+=pv.z*pv.z; q4[3]+=pv.w*pv.w;
    }
    *(float4*)&redS[h*2 + gh][4*f32] = make_float4(s4[0], s4[1], s4[2], s4[3]);
    *(float4*)&redQ[h*2 + gh][4*f32] = make_float4(q4[0], q4[1], q4[2], q4[3]);
    __syncthreads();
    if (t < 128) {
        float s = 0.f;
        #pragma unroll
        for (int j = 0; j < 8; j++) s += redS[j][t];
        p3[bid*256 + t] = s;
    } else {
        int f = t - 128;
        float qq = 0.f;
        #pragma unroll
        for (int j = 0; j < 8; j++) qq += redQ[j][f];
        p3[bid*256 + 128 + f] = qq;
    }
}

// ---------------- K6a: BN3 partial reduction ----------------
__global__ __launch_bounds__(256) void k6a(const float* __restrict__ p3, float* __restrict__ r3)
{
    int j = blockIdx.x, f = threadIdx.x;
    float s = 0.f;
    for (int r = j*16; r < (j+1)*16; r++) s += p3[r*256 + f];
    r3[j*256 + f] = s;
}

// ---------------- K7: folds BN3-finalize + head. thread per graph ----------------
__global__ __launch_bounds__(256) void k7_head(
    const float* __restrict__ pre3, const float* __restrict__ R3,
    const float* __restrict__ g3, const float* __restrict__ bt3,
    const float* __restrict__ W2h, const float* __restrict__ b2h,
    const float* __restrict__ W3h, const float* __restrict__ b3h,
    float* __restrict__ out)
{
    __shared__ float A3s[128], D3s[128];
    int t = threadIdx.x;
    if (t < 128) {
        float s = 0.f, q = 0.f;
        for (int j = 0; j < 64; j++) { s += R3[j*256 + t]; q += R3[j*256 + 128 + t]; }
        float m = s / (float)BGR;
        float v = q / (float)BGR - m*m;
        float a = g3[t] * rsqrtf(v + EPS);
        A3s[t] = a;
        D3s[t] = bt3[t] - a*m;
    }
    __syncthreads();

    int g = blockIdx.x*256 + t;
    float accj[32];
    #pragma unroll
    for (int j = 0; j < 32; j++) accj[j] = b2h[j];
    const float* p3 = pre3 + (size_t)g*128;
    #pragma unroll 2
    for (int f4 = 0; f4 < 128; f4 += 4) {
        float4 pv = *(const float4*)(p3 + f4);
        float y0 = fmaxf(fmaf(A3s[f4+0], pv.x, D3s[f4+0]), 0.f);
        float y1 = fmaxf(fmaf(A3s[f4+1], pv.y, D3s[f4+1]), 0.f);
        float y2 = fmaxf(fmaf(A3s[f4+2], pv.z, D3s[f4+2]), 0.f);
        float y3 = fmaxf(fmaf(A3s[f4+3], pv.w, D3s[f4+3]), 0.f);
        #pragma unroll
        for (int j = 0; j < 32; j++) {
            accj[j] = fmaf(y0, W2h[(f4+0)*32+j], accj[j]);
            accj[j] = fmaf(y1, W2h[(f4+1)*32+j], accj[j]);
            accj[j] = fmaf(y2, W2h[(f4+2)*32+j], accj[j]);
            accj[j] = fmaf(y3, W2h[(f4+3)*32+j], accj[j]);
        }
    }
    float o0 = b3h[0], o1 = b3h[1];
    #pragma unroll
    for (int j = 0; j < 32; j++) {
        float yj = fmaxf(accj[j], 0.f);
        o0 = fmaf(yj, W3h[j*2+0], o0);
        o1 = fmaf(yj, W3h[j*2+1], o1);
    }
    ((float2*)out)[g] = make_float2(o0, o1);
}

extern "C" void kernel_launch(void* const* d_in, const int* in_sizes, int n_in,
                              void* d_out, int out_size, void* d_ws, size_t ws_size,
                              hipStream_t stream)
{
    (void)in_sizes; (void)n_in; (void)out_size; (void)ws_size;
    const float* x    = (const float*)d_in[0];
    const float* ew   = (const float*)d_in[1];
    const int*   eif  = (const int*)d_in[2];
    const int*   eis  = (const int*)d_in[3];
    const float* W1   = (const float*)d_in[4];
    // d_in[5] = b1: cancels exactly inside BN1 (mean subtraction) — unused
    const float* g1   = (const float*)d_in[6];
    const float* bt1  = (const float*)d_in[7];
    const float* W2   = (const float*)d_in[8];
    const float* b2   = (const float*)d_in[9];
    const float* g2   = (const float*)d_in[10];
    const float* bt2  = (const float*)d_in[11];
    const float* l1W  = (const float*)d_in[12];
    const float* l1b  = (const float*)d_in[13];
    const float* g3   = (const float*)d_in[14];
    const float* bt3  = (const float*)d_in[15];
    const float* l2W  = (const float*)d_in[16];
    const float* l2b  = (const float*)d_in[17];
    const float* l3W  = (const float*)d_in[18];
    const float* l3b  = (const float*)d_in[19];
    float* out = (float*)d_out;
    float* ws  = (float*)d_ws;

    const int* srcf = eif;  const int* dstf = eif + BGR*EF;
    const int* srcs = eis;  const int* dsts = eis + BGR*ES;

    float* U    = ws + WS_U;
    float* PRE2 = ws + WS_PRE2;
    float* PRE3 = ws + WS_PRE3;
    float* P3   = ws + WS_P3;
    float* R3   = ws + WS_R3;
    float* P1   = ws + WS_P1;
    float* R2   = ws + WS_R2;
    float* WP   = ws + WS_WP;
    float* TB   = ws + WS_TB;
    float4* TSEG= (float4*)(ws + WS_TSEG);

    k1_gcn1<<<BGR/4, 256, 0, stream>>>(x, ew, srcf, dstf, U);
    kr1<<<160, 256, 0, stream>>>(U, P1, l1W, WP);
    k2c<<<1, 256, 0, stream>>>(P1, W1, g1, bt1, W2, TB, TSEG);
    k3b<<<BGR/4, 256, 0, stream>>>(U, srcs, dsts, TB, TSEG, b2, (float2*)PRE2);
    kr2<<<320, 256, 0, stream>>>((const float2*)PRE2, R2);
    k5_lin1<<<1024, 256, 0, stream>>>((const float2*)PRE2, R2, g2, bt2, WP, l1b, PRE3, P3);
    k6a<<<64, 256, 0, stream>>>(P3, R3);
    k7_head<<<BGR/256, 256, 0, stream>>>(PRE3, R3, g3, bt3, l2W, l2b, l3W, l3b, out);
}